// Round 10
// baseline (180.955 us; speedup 1.0000x reference)
//
#include <hip/hip_runtime.h>

typedef __bf16 bf16x8 __attribute__((ext_vector_type(8)));
typedef __bf16 bf16x4 __attribute__((ext_vector_type(4)));
typedef float f32x4 __attribute__((ext_vector_type(4)));

#define SLOTW 260  // per-row partial-slot stride floats (>= 4*NTv_max=256)

#define GLOAD_LDS16(g, l)                                                      \
  __builtin_amdgcn_global_load_lds(                                            \
      (const __attribute__((address_space(1))) void*)(g),                      \
      (__attribute__((address_space(3))) void*)(l), 16, 0, 0)

// ---------------- K1: codes + stable label-partition scan (1 block) ---------
// dst[r] = gathered index for valid rows, grouped by label (0,1,2 ascending).
// hdr = {M, Mpad, NTv, ntri, C0, C1, C2}. Also zeroes fng pad rows and sets
// gcode pad = 255 (replaces host-side memsets).
__global__ __launch_bounds__(1024) void k_scan(
    const int* __restrict__ labels, const int* __restrict__ bad,
    unsigned char* __restrict__ code, int* __restrict__ dst,
    int* __restrict__ hdr, __bf16* __restrict__ fng,
    unsigned char* __restrict__ gcode, int Nv, int Dv) {
  const int t = threadIdx.x;
  const int per = Nv >> 10;  // rows per thread (8 for 8192)
  const int base = t * per;
  unsigned char lc[8];
  int cnt[3] = {0, 0, 0};
  for (int k = 0; k < per; ++k) {
    const int r = base + k;
    const unsigned char c =
        (bad[r] == 0) ? (unsigned char)labels[r] : (unsigned char)255;
    lc[k] = c;
    code[r] = c;
    if (c <= 2) cnt[c]++;
  }
  __shared__ int s0[1024], s1[1024], s2[1024];
  s0[t] = cnt[0];
  s1[t] = cnt[1];
  s2[t] = cnt[2];
  __syncthreads();
  for (int off = 1; off < 1024; off <<= 1) {
    const int a0 = (t >= off) ? s0[t - off] : 0;
    const int a1 = (t >= off) ? s1[t - off] : 0;
    const int a2 = (t >= off) ? s2[t - off] : 0;
    __syncthreads();
    s0[t] += a0;
    s1[t] += a1;
    s2[t] += a2;
    __syncthreads();
  }
  const int C0 = s0[1023], C1 = s1[1023], C2 = s2[1023];
  int run[3];
  run[0] = s0[t] - cnt[0];
  run[1] = C0 + s1[t] - cnt[1];
  run[2] = C0 + C1 + s2[t] - cnt[2];
  for (int k = 0; k < per; ++k) {
    const int c = lc[k];
    dst[base + k] = (c <= 2) ? run[c]++ : -1;
  }
  const int M = C0 + C1 + C2;
  const int Mpad = (M + 127) & ~127;
  if (t == 0) {
    const int NTv = Mpad >> 7;
    hdr[0] = M;
    hdr[1] = Mpad;
    hdr[2] = NTv;
    hdr[3] = NTv * (NTv + 1) / 2;
    hdr[4] = C0;
    hdr[5] = C1;
    hdr[6] = C2;
  }
  // pad rows: fng zero (MFMA reads them), gcode 255 (self-masking)
  for (int i = M + t; i < Mpad; i += 1024) gcode[i] = 255;
  const int nv4 = (Mpad - M) * (Dv >> 3);  // float4 chunks in pad region
  float4* fp = (float4*)(fng + (size_t)M * Dv);
  const float4 z = {0.f, 0.f, 0.f, 0.f};
  for (int i = t; i < nv4; i += 1024) fp[i] = z;
}

// ---------------- K2: normalize valid rows -> bf16, gathered+sorted ---------
__global__ __launch_bounds__(128) void k_norm(const float* __restrict__ X,
                                              const unsigned char* __restrict__
                                                  code,
                                              const int* __restrict__ dst,
                                              __bf16* __restrict__ fng,
                                              unsigned char* __restrict__ gcode,
                                              int Dv) {
  const int row = blockIdx.x;
  const unsigned char c = code[row];
  if (c > 2) return;  // invalid: skipped entirely
  const int g = dst[row];
  const int t = threadIdx.x;
  const float4* xr = (const float4*)(X + (size_t)row * Dv);
  float ss = 0.f;
  const int nv4 = Dv >> 2;
  for (int idx = t; idx < nv4; idx += 128) {
    float4 v = xr[idx];
    ss += v.x * v.x + v.y * v.y + v.z * v.z + v.w * v.w;
  }
#pragma unroll
  for (int off = 32; off; off >>= 1) ss += __shfl_down(ss, off);
  __shared__ float sred[2];
  if ((t & 63) == 0) sred[t >> 6] = ss;
  __syncthreads();
  const float inv = 1.0f / sqrtf(sred[0] + sred[1]);
  for (int idx = t; idx < nv4; idx += 128) {
    float4 v = xr[idx];
    bf16x4 o;
    o.x = (__bf16)(v.x * inv);
    o.y = (__bf16)(v.y * inv);
    o.z = (__bf16)(v.z * inv);
    o.w = (__bf16)(v.w * inv);
    *(bf16x4*)(fng + (size_t)g * Dv + idx * 4) = o;
  }
  if (t == 0) gcode[g] = c;
}

__device__ __forceinline__ void tri_decode(int blk, int NT, int& bi, int& bj) {
  int b = 0, rem = blk, span = NT;
  while (rem >= span) {
    rem -= span;
    b++;
    span--;
  }
  bi = b;
  bj = b + rem;
}

__device__ __forceinline__ bool tile_overlap(const unsigned char* gcode,
                                             size_t sA, size_t rowB) {
  const int la0 = gcode[sA], la1 = gcode[sA + 63];
  const int lb0 = gcode[rowB], lb1 = gcode[rowB + 127];
  const int hiA = la1 > 2 ? 2 : la1;
  const int hiB = lb1 > 2 ? 2 : lb1;
  const int lo = la0 > lb0 ? la0 : lb0;
  const int hi = hiA < hiB ? hiA : hiB;
  return (la0 <= 2) && (lb0 <= 2) && (lo <= hi);
}

// ---------------- K3: pass 1 — exp-sums, 64x128 half-tiles, 2 waves ---------
// 128-thread blocks: wave w computes rows [h*64+w*32, +32) x all 128 cols
// (2x8 accs of 16x16x32 MFMA -> 10 ds_read per 16 MFMA, vs 6:8 before).
// Coalesced global_load_lds staging, double-buffered (24 KB LDS -> 6
// blocks/CU). Stores Sc (fp16 half-tile) for label-overlap tiles so pass 2
// needs no MFMA.
// Slot ownership (P not pre-zeroed — every slot < 4*NTv single-written):
//   row g (owned by exactly one (h,wave)): slots bj*4+0 real, +1..3 zero
//   col j (bi<bj): slot bi*4 + h*2 + wave   [4 real partials fill bi*4..+3]
__global__ __launch_bounds__(128) void k_p1(const __bf16* __restrict__ fng,
                                            const unsigned char* __restrict__
                                                gcode,
                                            const int* __restrict__ hdr,
                                            float* __restrict__ P,
                                            _Float16* __restrict__ Sc, int Dv) {
  const int NTv = hdr[2];
  if ((int)blockIdx.x >= hdr[3]) return;
  int bi, bj;
  tri_decode(blockIdx.x, NTv, bi, bj);
  const int h = blockIdx.y;
  const size_t sA = (size_t)bi * 128 + h * 64;
  const size_t rowB = (size_t)bj * 128;
  __shared__ __align__(16) __bf16 As[2][64 * 32];
  __shared__ __align__(16) __bf16 Bs[2][128 * 32];

  const int t = threadIdx.x;
  const int lane = t & 63;
  const int wave = t >> 6;
  const int quad = lane >> 4;
  const int l16 = lane & 15;
  const int wr = wave * 32;  // wave's first row within the 64-row half

  f32x4 acc[2][8] = {};
  auto stage = [&](int k0, int b) {
    // A: chunks 0..255 (64 rows x 4 chunks); B: chunks 0..511
#pragma unroll
    for (int it = 0; it < 2; ++it) {
      const int c = t + it * 128;
      GLOAD_LDS16(fng + (sA + (c >> 2)) * Dv + k0 + (c & 3) * 8,
                  &As[b][(size_t)(it * 128 + wave * 64) * 8]);
    }
#pragma unroll
    for (int it = 0; it < 4; ++it) {
      const int c = t + it * 128;
      GLOAD_LDS16(fng + (rowB + (c >> 2)) * Dv + k0 + (c & 3) * 8,
                  &Bs[b][(size_t)(it * 128 + wave * 64) * 8]);
    }
  };
  stage(0, 0);
  int buf = 0;
  for (int k0 = 0; k0 < Dv; k0 += 32) {
    __syncthreads();  // drains vmcnt: buf's loads complete; prev reads done
    if (k0 + 32 < Dv) stage(k0 + 32, buf ^ 1);  // flies under this iter's MFMA
    bf16x8 af[2], bfv[8];
#pragma unroll
    for (int mi = 0; mi < 2; ++mi)
      af[mi] = *(const bf16x8*)&As[buf][(wr + mi * 16 + l16) * 32 + quad * 8];
#pragma unroll
    for (int ni = 0; ni < 8; ++ni)
      bfv[ni] = *(const bf16x8*)&Bs[buf][(ni * 16 + l16) * 32 + quad * 8];
#pragma unroll
    for (int mi = 0; mi < 2; ++mi)
#pragma unroll
      for (int ni = 0; ni < 8; ++ni)
        acc[mi][ni] = __builtin_amdgcn_mfma_f32_16x16x32_bf16(
            af[mi], bfv[ni], acc[mi][ni], 0, 0, 0);
    buf ^= 1;
  }

  // C/D layout (verified m89/m91): col = lane&15, row = quad*4 + reg
  unsigned char ca[8], cb[8];
#pragma unroll
  for (int mi = 0; mi < 2; ++mi)
#pragma unroll
    for (int r = 0; r < 4; ++r)
      ca[mi * 4 + r] = gcode[sA + wr + mi * 16 + quad * 4 + r];
#pragma unroll
  for (int ni = 0; ni < 8; ++ni) cb[ni] = gcode[rowB + ni * 16 + l16];
  const bool ov = tile_overlap(gcode, sA, rowB);
  _Float16* St = Sc + ((size_t)blockIdx.x * 2 + h) * 8192;

  float rowsum[8] = {};
  float colsum[8] = {};
#pragma unroll
  for (int mi = 0; mi < 2; ++mi)
#pragma unroll
    for (int ni = 0; ni < 8; ++ni)
#pragma unroll
      for (int r = 0; r < 4; ++r) {
        const float s = acc[mi][ni][r] * 10.0f;
        const float ex = __expf(s);
        const int a = ca[mi * 4 + r], b = cb[ni];
        const bool diff = a != b;
        rowsum[mi * 4 + r] += (b <= 2 && diff) ? ex : 0.f;
        colsum[ni] += (a <= 2 && diff) ? ex : 0.f;
        if (ov)
          St[(wr + mi * 16 + quad * 4 + r) * 128 + ni * 16 + l16] =
              (_Float16)s;
      }
  // row sums: reduce across the 16 l16 lanes (same quad)
#pragma unroll
  for (int off = 1; off < 16; off <<= 1)
#pragma unroll
    for (int k = 0; k < 8; ++k) rowsum[k] += __shfl_xor(rowsum[k], off);
  if (l16 == 0)
#pragma unroll
    for (int k = 0; k < 8; ++k) {
      const size_t base =
          (sA + wr + (k >> 2) * 16 + quad * 4 + (k & 3)) * SLOTW + bj * 4;
      P[base + 0] = rowsum[k];
      P[base + 1] = 0.f;
      P[base + 2] = 0.f;
      P[base + 3] = 0.f;
    }
  if (bi != bj) {
    // col sums: reduce across the 4 quads (xor 16, 32)
#pragma unroll
    for (int off = 16; off < 64; off <<= 1)
#pragma unroll
      for (int ni = 0; ni < 8; ++ni) colsum[ni] += __shfl_xor(colsum[ni], off);
    if (quad == 0)
#pragma unroll
      for (int ni = 0; ni < 8; ++ni)
        P[(rowB + ni * 16 + l16) * SLOTW + bi * 4 + h * 2 + wave] = colsum[ni];
  }
}

// ---------------- K4: slot reduce: out[g] = sum_{slot<4*NTv} ----------------
__global__ __launch_bounds__(256) void k_red(const float* __restrict__ P,
                                             float* __restrict__ out,
                                             const int* __restrict__ hdr,
                                             int Nv) {
  const int g = blockIdx.x * 256 + threadIdx.x;
  if (g >= Nv) return;
  const int ns = hdr[2] * 4;
  float s = 0.f;
  const float4* p = (const float4*)(P + (size_t)g * SLOTW);
  for (int k = 0; k < (ns >> 2); ++k) {
    const float4 v = p[k];
    s += v.x + v.y + v.z + v.w;
  }
  out[g] = s;
}

// ---------------- K5: pass 2 — positive log-terms from stored Sc ------------
// No MFMA: reads the fp16 half-tile p1 stored (only for overlap tiles).
// Slot ownership (P2): row g (half h): all 4 slots bj*4+{0..3} (real at h*2,
// zeros elsewhere); col j: slots bi*4+h*2+{0,1} (real at +0, zero at +1).
// Inactive blocks zero their owned slots — deterministic, no memset.
__global__ __launch_bounds__(256) void k_p2(
    const unsigned char* __restrict__ gcode, const int* __restrict__ hdr,
    const float* __restrict__ E, float* __restrict__ P2,
    const _Float16* __restrict__ Sc) {
  const int NTv = hdr[2];
  if ((int)blockIdx.x >= hdr[3]) return;
  int bi, bj;
  tri_decode(blockIdx.x, NTv, bi, bj);
  const int h = blockIdx.y;
  const size_t sA = (size_t)bi * 128 + h * 64;
  const size_t rowB = (size_t)bj * 128;
  const int t = threadIdx.x;
  const bool diag = (bi == bj);

  if (!tile_overlap(gcode, sA, rowB)) {
    if (t < 64) {
      const size_t base = (sA + t) * SLOTW + bj * 4;
      P2[base] = 0.f;
      P2[base + 1] = 0.f;
      P2[base + 2] = 0.f;
      P2[base + 3] = 0.f;
    } else if (t < 192 && !diag) {
      const size_t base = (rowB + t - 64) * SLOTW + bi * 4 + h * 2;
      P2[base] = 0.f;
      P2[base + 1] = 0.f;
    }
    return;
  }

  const _Float16* St = Sc + ((size_t)blockIdx.x * 2 + h) * 8192;
  const int l8 = t & 15;  // column-chunk: cols l8*8 .. l8*8+7
  unsigned char cb[8];
  float eB[8];
  {
    const uint2 cv = *(const uint2*)(gcode + rowB + l8 * 8);
    const unsigned char* cp = (const unsigned char*)&cv;
#pragma unroll
    for (int e = 0; e < 8; ++e) cb[e] = cp[e];
    const float4 e0 = *(const float4*)(E + rowB + l8 * 8);
    const float4 e1 = *(const float4*)(E + rowB + l8 * 8 + 4);
    eB[0] = e0.x; eB[1] = e0.y; eB[2] = e0.z; eB[3] = e0.w;
    eB[4] = e1.x; eB[5] = e1.y; eB[6] = e1.z; eB[7] = e1.w;
  }
  float colsum[8] = {};
#pragma unroll
  for (int k = 0; k < 4; ++k) {
    const int row = k * 16 + (t >> 4);
    const int a = gcode[sA + row];
    const float eA = E[sA + row];
    const float4 sv = *(const float4*)(St + row * 128 + l8 * 8);
    const _Float16* hp = (const _Float16*)&sv;
    float rsum = 0.f;
#pragma unroll
    for (int e = 0; e < 8; ++e) {
      const int col = l8 * 8 + e;
      const float em = __expf(-(float)hp[e]);
      const bool pos =
          (a == cb[e]) && (cb[e] <= 2) && !(diag && (row + h * 64) == col);
      rsum += pos ? __logf(1.f + eA * em) : 0.f;
      colsum[e] += pos ? __logf(1.f + eB[e] * em) : 0.f;
    }
#pragma unroll
    for (int off = 1; off < 16; off <<= 1) rsum += __shfl_xor(rsum, off);
    if (l8 == 0) {
      const size_t base = (sA + row) * SLOTW + bj * 4;
      P2[base + h * 2] = rsum;
      P2[base + h * 2 + 1] = 0.f;
      P2[base + (1 - h) * 2] = 0.f;
      P2[base + (1 - h) * 2 + 1] = 0.f;
    }
  }
  // cross-wave col reduction via LDS (stride 17: conflict-free)
  __shared__ float colpart[128 * 17];
#pragma unroll
  for (int e = 0; e < 8; ++e) colpart[(l8 * 8 + e) * 17 + (t >> 4)] = colsum[e];
  __syncthreads();
  if (t < 128 && !diag) {
    float cs = 0.f;
#pragma unroll
    for (int i = 0; i < 16; ++i) cs += colpart[t * 17 + i];
    const size_t base = (rowB + t) * SLOTW + bi * 4 + h * 2;
    P2[base] = cs;
    P2[base + 1] = 0.f;
  }
}

// ---------------- K6: final deterministic reduce ----------------------------
__global__ __launch_bounds__(256) void k_final(
    const float* __restrict__ psum, const float* __restrict__ E,
    const unsigned char* __restrict__ code, const int* __restrict__ dst,
    const int* __restrict__ hdr, float* __restrict__ out, int Nv) {
  const int t = threadIdx.x;
  const int c0 = hdr[4], c1 = hdr[5], c2 = hdr[6];
  const int validTotal = c0 + c1 + c2;
  const float em10 = __expf(-10.0f);
  double s = 0.0;
  int c = 0;
  for (int i = t; i < Nv; i += 256) {
    const int myc = code[i];
    if (myc > 2) continue;  // invalid anchor: not processed
    const int cmy = (myc == 0) ? c0 : ((myc == 1) ? c1 : c2);
    if (validTotal - cmy == 0) continue;  // no negatives: not processed
    const int g = dst[i];
    const int pos_cnt = cmy - 1;
    if (pos_cnt > 0) {
      s += (double)(psum[g] / (float)pos_cnt);
      c += 1;
    } else {
      s += (double)__logf(1.f + E[g] * em10);  // logaddexp(1/T,lse) - 1/T
    }
  }
#pragma unroll
  for (int off = 32; off; off >>= 1) {
    s += __shfl_down(s, off);
    c += __shfl_down(c, off);
  }
  __shared__ double sd[4];
  __shared__ int si[4];
  if ((t & 63) == 0) {
    sd[t >> 6] = s;
    si[t >> 6] = c;
  }
  __syncthreads();
  if (t == 0) {
    const double st = sd[0] + sd[1] + sd[2] + sd[3];
    const int ct = 1 + si[0] + si[1] + si[2] + si[3];
    out[0] = (float)(st / (double)ct);
  }
}

extern "C" void kernel_launch(void* const* d_in, const int* in_sizes, int n_in,
                              void* d_out, int out_size, void* d_ws,
                              size_t ws_size, hipStream_t stream) {
  const float* X = (const float*)d_in[0];
  const int* labels = (const int*)d_in[1];
  const int* bad = (const int*)d_in[2];
  const int Nv = in_sizes[1];
  const int Dv = in_sizes[0] / Nv;

  size_t off = 0;
  auto alloc = [&](size_t bytes) -> void* {
    size_t p = (off + 255) & ~(size_t)255;
    off = p + bytes;
    return (void*)((char*)d_ws + p);
  };
  const int NT = Nv / 128;
  const int ntri_max = NT * (NT + 1) / 2;
  __bf16* fng = (__bf16*)alloc((size_t)Nv * Dv * 2);
  float* P = (float*)alloc((size_t)Nv * SLOTW * 4);
  float* P2 = (float*)alloc((size_t)Nv * SLOTW * 4);
  _Float16* Sc = (_Float16*)alloc((size_t)ntri_max * 2 * 8192 * 2);
  float* E = (float*)alloc((size_t)Nv * 4);
  float* psum = (float*)alloc((size_t)Nv * 4);
  int* dst = (int*)alloc((size_t)Nv * 4);
  unsigned char* code = (unsigned char*)alloc((size_t)Nv);
  unsigned char* gcode = (unsigned char*)alloc((size_t)Nv);
  int* hdr = (int*)alloc(64);
  if (off > ws_size) return;  // scratch too small: fail loudly at validation

  k_scan<<<1, 1024, 0, stream>>>(labels, bad, code, dst, hdr, fng, gcode, Nv,
                                 Dv);
  k_norm<<<Nv, 128, 0, stream>>>(X, code, dst, fng, gcode, Dv);
  dim3 gp(ntri_max, 2);
  k_p1<<<gp, 128, 0, stream>>>(fng, gcode, hdr, P, Sc, Dv);
  k_red<<<(Nv + 255) / 256, 256, 0, stream>>>(P, E, hdr, Nv);
  k_p2<<<gp, 256, 0, stream>>>(gcode, hdr, E, P2, Sc);
  k_red<<<(Nv + 255) / 256, 256, 0, stream>>>(P2, psum, hdr, Nv);
  k_final<<<1, 256, 0, stream>>>(psum, E, code, dst, hdr, (float*)d_out, Nv);
}

// Round 11
// 179.058 us; speedup vs baseline: 1.0106x; 1.0106x over previous
//
#include <hip/hip_runtime.h>

typedef __bf16 bf16x8 __attribute__((ext_vector_type(8)));
typedef __bf16 bf16x4 __attribute__((ext_vector_type(4)));
typedef float f32x4 __attribute__((ext_vector_type(4)));

#define SLOTW 260  // per-row partial-slot stride floats (>= 4*NTv_max=256)

#define GLOAD_LDS16(g, l)                                                      \
  __builtin_amdgcn_global_load_lds(                                            \
      (const __attribute__((address_space(1))) void*)(g),                      \
      (__attribute__((address_space(3))) void*)(l), 16, 0, 0)

// ---------------- K1: codes + stable label-partition scan (1 block) ---------
// dst[r] = gathered index for valid rows, grouped by label (0,1,2 ascending).
// hdr = {M, Mpad, NTv, ntri, C0, C1, C2}. Also zeroes fng pad rows and sets
// gcode pad = 255 (replaces host-side memsets).
__global__ __launch_bounds__(1024) void k_scan(
    const int* __restrict__ labels, const int* __restrict__ bad,
    unsigned char* __restrict__ code, int* __restrict__ dst,
    int* __restrict__ hdr, __bf16* __restrict__ fng,
    unsigned char* __restrict__ gcode, int Nv, int Dv) {
  const int t = threadIdx.x;
  const int per = Nv >> 10;  // rows per thread (8 for 8192)
  const int base = t * per;
  unsigned char lc[8];
  int cnt[3] = {0, 0, 0};
  for (int k = 0; k < per; ++k) {
    const int r = base + k;
    const unsigned char c =
        (bad[r] == 0) ? (unsigned char)labels[r] : (unsigned char)255;
    lc[k] = c;
    code[r] = c;
    if (c <= 2) cnt[c]++;
  }
  __shared__ int s0[1024], s1[1024], s2[1024];
  s0[t] = cnt[0];
  s1[t] = cnt[1];
  s2[t] = cnt[2];
  __syncthreads();
  for (int off = 1; off < 1024; off <<= 1) {
    const int a0 = (t >= off) ? s0[t - off] : 0;
    const int a1 = (t >= off) ? s1[t - off] : 0;
    const int a2 = (t >= off) ? s2[t - off] : 0;
    __syncthreads();
    s0[t] += a0;
    s1[t] += a1;
    s2[t] += a2;
    __syncthreads();
  }
  const int C0 = s0[1023], C1 = s1[1023], C2 = s2[1023];
  int run[3];
  run[0] = s0[t] - cnt[0];
  run[1] = C0 + s1[t] - cnt[1];
  run[2] = C0 + C1 + s2[t] - cnt[2];
  for (int k = 0; k < per; ++k) {
    const int c = lc[k];
    dst[base + k] = (c <= 2) ? run[c]++ : -1;
  }
  const int M = C0 + C1 + C2;
  const int Mpad = (M + 127) & ~127;
  if (t == 0) {
    const int NTv = Mpad >> 7;
    hdr[0] = M;
    hdr[1] = Mpad;
    hdr[2] = NTv;
    hdr[3] = NTv * (NTv + 1) / 2;
    hdr[4] = C0;
    hdr[5] = C1;
    hdr[6] = C2;
  }
  // pad rows: fng zero (MFMA reads them), gcode 255 (self-masking)
  for (int i = M + t; i < Mpad; i += 1024) gcode[i] = 255;
  const int nv4 = (Mpad - M) * (Dv >> 3);  // float4 chunks in pad region
  float4* fp = (float4*)(fng + (size_t)M * Dv);
  const float4 z = {0.f, 0.f, 0.f, 0.f};
  for (int i = t; i < nv4; i += 1024) fp[i] = z;
}

// ---------------- K2: normalize valid rows -> bf16, gathered+sorted ---------
__global__ __launch_bounds__(128) void k_norm(const float* __restrict__ X,
                                              const unsigned char* __restrict__
                                                  code,
                                              const int* __restrict__ dst,
                                              __bf16* __restrict__ fng,
                                              unsigned char* __restrict__ gcode,
                                              int Dv) {
  const int row = blockIdx.x;
  const unsigned char c = code[row];
  if (c > 2) return;  // invalid: skipped entirely
  const int g = dst[row];
  const int t = threadIdx.x;
  const float4* xr = (const float4*)(X + (size_t)row * Dv);
  float ss = 0.f;
  const int nv4 = Dv >> 2;
  for (int idx = t; idx < nv4; idx += 128) {
    float4 v = xr[idx];
    ss += v.x * v.x + v.y * v.y + v.z * v.z + v.w * v.w;
  }
#pragma unroll
  for (int off = 32; off; off >>= 1) ss += __shfl_down(ss, off);
  __shared__ float sred[2];
  if ((t & 63) == 0) sred[t >> 6] = ss;
  __syncthreads();
  const float inv = 1.0f / sqrtf(sred[0] + sred[1]);
  // one 16B bf16x8 store per 8 elements
  const int nv8 = Dv >> 3;
  for (int idx = t; idx < nv8; idx += 128) {
    const float4 v0 = xr[idx * 2];
    const float4 v1 = xr[idx * 2 + 1];
    bf16x8 o;
    o[0] = (__bf16)(v0.x * inv);
    o[1] = (__bf16)(v0.y * inv);
    o[2] = (__bf16)(v0.z * inv);
    o[3] = (__bf16)(v0.w * inv);
    o[4] = (__bf16)(v1.x * inv);
    o[5] = (__bf16)(v1.y * inv);
    o[6] = (__bf16)(v1.z * inv);
    o[7] = (__bf16)(v1.w * inv);
    *(bf16x8*)(fng + (size_t)g * Dv + idx * 8) = o;
  }
  if (t == 0) gcode[g] = c;
}

__device__ __forceinline__ void tri_decode(int blk, int NT, int& bi, int& bj) {
  int b = 0, rem = blk, span = NT;
  while (rem >= span) {
    rem -= span;
    b++;
    span--;
  }
  bi = b;
  bj = b + rem;
}

__device__ __forceinline__ bool tile_overlap(const unsigned char* gcode,
                                             size_t sA, size_t rowB) {
  const int la0 = gcode[sA], la1 = gcode[sA + 63];
  const int lb0 = gcode[rowB], lb1 = gcode[rowB + 127];
  const int hiA = la1 > 2 ? 2 : la1;
  const int hiB = lb1 > 2 ? 2 : lb1;
  const int lo = la0 > lb0 ? la0 : lb0;
  const int hi = hiA < hiB ? hiA : hiB;
  return (la0 <= 2) && (lb0 <= 2) && (lo <= hi);
}

// ---------------- K3: pass 1 — exp-sums, 64x128 half-tiles ------------------
// R9 config (measured optimum of the concurrency x issue-ratio trade):
// 256-thr/4-wave blocks, wave = 32x64 (2x4 of 16x16x32 MFMA), coalesced
// global_load_lds staging, double-buffered, one barrier/iter. 24 KB LDS.
// Stores Sc (fp16 half-tile) for label-overlap tiles so pass 2 needs no MFMA.
// Slot ownership (P not pre-zeroed — every slot < 4*NTv single-written):
//   rows of half h: real slot bj*4+h*2+(wave&1), zero slot bj*4+(1-h)*2+(wave&1)
//   cols (bi<bj): real slot bi*4+h*2+(wave>>1)   [all 4 across h x wavehalf]
__global__ __launch_bounds__(256) void k_p1(const __bf16* __restrict__ fng,
                                            const unsigned char* __restrict__
                                                gcode,
                                            const int* __restrict__ hdr,
                                            float* __restrict__ P,
                                            _Float16* __restrict__ Sc, int Dv) {
  const int NTv = hdr[2];
  if ((int)blockIdx.x >= hdr[3]) return;
  int bi, bj;
  tri_decode(blockIdx.x, NTv, bi, bj);
  const int h = blockIdx.y;
  const size_t sA = (size_t)bi * 128 + h * 64;
  const size_t rowB = (size_t)bj * 128;
  __shared__ __align__(16) __bf16 As[2][64 * 32];
  __shared__ __align__(16) __bf16 Bs[2][128 * 32];

  const int t = threadIdx.x;
  const int lane = t & 63;
  const int wave = t >> 6;
  const int quad = lane >> 4;
  const int l16 = lane & 15;
  const int wr = (wave >> 1) * 32;
  const int wc = (wave & 1) * 64;
  const int r4 = t >> 2, q4 = t & 3;
  const int r4b = (t + 256) >> 2, q4b = (t + 256) & 3;

  f32x4 acc[2][4] = {};
  auto stage = [&](int k0, int b) {
    GLOAD_LDS16(fng + (sA + r4) * Dv + k0 + q4 * 8,
                &As[b][(size_t)wave * 64 * 8]);
    GLOAD_LDS16(fng + (rowB + r4) * Dv + k0 + q4 * 8,
                &Bs[b][(size_t)wave * 64 * 8]);
    GLOAD_LDS16(fng + (rowB + r4b) * Dv + k0 + q4b * 8,
                &Bs[b][(size_t)(256 + wave * 64) * 8]);
  };
  stage(0, 0);
  int buf = 0;
  for (int k0 = 0; k0 < Dv; k0 += 32) {
    __syncthreads();  // drains vmcnt: buf's loads complete; prev reads done
    if (k0 + 32 < Dv) stage(k0 + 32, buf ^ 1);  // flies under this iter's MFMA
    bf16x8 af[2], bfv[4];
#pragma unroll
    for (int mi = 0; mi < 2; ++mi)
      af[mi] = *(const bf16x8*)&As[buf][(wr + mi * 16 + l16) * 32 + quad * 8];
#pragma unroll
    for (int ni = 0; ni < 4; ++ni)
      bfv[ni] = *(const bf16x8*)&Bs[buf][(wc + ni * 16 + l16) * 32 + quad * 8];
#pragma unroll
    for (int mi = 0; mi < 2; ++mi)
#pragma unroll
      for (int ni = 0; ni < 4; ++ni)
        acc[mi][ni] = __builtin_amdgcn_mfma_f32_16x16x32_bf16(
            af[mi], bfv[ni], acc[mi][ni], 0, 0, 0);
    buf ^= 1;
  }

  // C/D layout (verified m89/m91): col = lane&15, row = quad*4 + reg
  unsigned char ca[8], cb[4];
#pragma unroll
  for (int mi = 0; mi < 2; ++mi)
#pragma unroll
    for (int r = 0; r < 4; ++r)
      ca[mi * 4 + r] = gcode[sA + wr + mi * 16 + quad * 4 + r];
#pragma unroll
  for (int ni = 0; ni < 4; ++ni) cb[ni] = gcode[rowB + wc + ni * 16 + l16];
  const bool ov = tile_overlap(gcode, sA, rowB);

  float rowsum[8] = {};
  float colsum[4] = {};
  if (ov) {
    _Float16* St = Sc + ((size_t)blockIdx.x * 2 + h) * 8192;
#pragma unroll
    for (int mi = 0; mi < 2; ++mi)
#pragma unroll
      for (int ni = 0; ni < 4; ++ni)
#pragma unroll
        for (int r = 0; r < 4; ++r) {
          const float s = acc[mi][ni][r] * 10.0f;
          const float ex = __expf(s);
          const int a = ca[mi * 4 + r], b = cb[ni];
          const bool diff = a != b;
          rowsum[mi * 4 + r] += (b <= 2 && diff) ? ex : 0.f;
          colsum[ni] += (a <= 2 && diff) ? ex : 0.f;
          St[(wr + mi * 16 + quad * 4 + r) * 128 + wc + ni * 16 + l16] =
              (_Float16)s;
        }
  } else {
#pragma unroll
    for (int mi = 0; mi < 2; ++mi)
#pragma unroll
      for (int ni = 0; ni < 4; ++ni)
#pragma unroll
        for (int r = 0; r < 4; ++r) {
          const float s = acc[mi][ni][r] * 10.0f;
          const float ex = __expf(s);
          const int a = ca[mi * 4 + r], b = cb[ni];
          const bool diff = a != b;
          rowsum[mi * 4 + r] += (b <= 2 && diff) ? ex : 0.f;
          colsum[ni] += (a <= 2 && diff) ? ex : 0.f;
        }
  }
#pragma unroll
  for (int off = 1; off < 16; off <<= 1)
#pragma unroll
    for (int k = 0; k < 8; ++k) rowsum[k] += __shfl_xor(rowsum[k], off);
  if (l16 == 0)
#pragma unroll
    for (int k = 0; k < 8; ++k) {
      const size_t base =
          (sA + wr + (k >> 2) * 16 + quad * 4 + (k & 3)) * SLOTW + bj * 4;
      P[base + h * 2 + (wave & 1)] = rowsum[k];
      P[base + (1 - h) * 2 + (wave & 1)] = 0.f;
    }
  if (bi != bj) {
#pragma unroll
    for (int off = 16; off < 64; off <<= 1)
#pragma unroll
      for (int ni = 0; ni < 4; ++ni) colsum[ni] += __shfl_xor(colsum[ni], off);
    if (quad == 0)
#pragma unroll
      for (int ni = 0; ni < 4; ++ni)
        P[(rowB + wc + ni * 16 + l16) * SLOTW + bi * 4 + h * 2 + (wave >> 1)] =
            colsum[ni];
  }
}

// ---------------- K4: slot reduce: out[g] = sum_{slot<4*NTv} ----------------
__global__ __launch_bounds__(256) void k_red(const float* __restrict__ P,
                                             float* __restrict__ out,
                                             const int* __restrict__ hdr,
                                             int Nv) {
  const int g = blockIdx.x * 256 + threadIdx.x;
  if (g >= Nv || g >= hdr[1]) return;  // only gathered rows matter
  const int ns = hdr[2] * 4;
  float s = 0.f;
  const float4* p = (const float4*)(P + (size_t)g * SLOTW);
  for (int k = 0; k < (ns >> 2); ++k) {
    const float4 v = p[k];
    s += v.x + v.y + v.z + v.w;
  }
  out[g] = s;
}

// ---------------- K5: pass 2 — positive log-terms from stored Sc ------------
// No MFMA: reads the fp16 half-tile p1 stored (only for overlap tiles).
// Slot ownership (P2): row g (half h): all 4 slots bj*4+{0..3} (real at h*2,
// zeros elsewhere); col j: slots bi*4+h*2+{0,1} (real at +0, zero at +1).
// Inactive blocks zero their owned slots — deterministic, no memset.
__global__ __launch_bounds__(256) void k_p2(
    const unsigned char* __restrict__ gcode, const int* __restrict__ hdr,
    const float* __restrict__ E, float* __restrict__ P2,
    const _Float16* __restrict__ Sc) {
  const int NTv = hdr[2];
  if ((int)blockIdx.x >= hdr[3]) return;
  int bi, bj;
  tri_decode(blockIdx.x, NTv, bi, bj);
  const int h = blockIdx.y;
  const size_t sA = (size_t)bi * 128 + h * 64;
  const size_t rowB = (size_t)bj * 128;
  const int t = threadIdx.x;
  const bool diag = (bi == bj);

  if (!tile_overlap(gcode, sA, rowB)) {
    if (t < 64) {
      const size_t base = (sA + t) * SLOTW + bj * 4;
      P2[base] = 0.f;
      P2[base + 1] = 0.f;
      P2[base + 2] = 0.f;
      P2[base + 3] = 0.f;
    } else if (t < 192 && !diag) {
      const size_t base = (rowB + t - 64) * SLOTW + bi * 4 + h * 2;
      P2[base] = 0.f;
      P2[base + 1] = 0.f;
    }
    return;
  }

  const _Float16* St = Sc + ((size_t)blockIdx.x * 2 + h) * 8192;
  const int l8 = t & 15;  // column-chunk: cols l8*8 .. l8*8+7
  unsigned char cb[8];
  float eB[8];
  {
    const uint2 cv = *(const uint2*)(gcode + rowB + l8 * 8);
    const unsigned char* cp = (const unsigned char*)&cv;
#pragma unroll
    for (int e = 0; e < 8; ++e) cb[e] = cp[e];
    const float4 e0 = *(const float4*)(E + rowB + l8 * 8);
    const float4 e1 = *(const float4*)(E + rowB + l8 * 8 + 4);
    eB[0] = e0.x; eB[1] = e0.y; eB[2] = e0.z; eB[3] = e0.w;
    eB[4] = e1.x; eB[5] = e1.y; eB[6] = e1.z; eB[7] = e1.w;
  }
  float colsum[8] = {};
#pragma unroll
  for (int k = 0; k < 4; ++k) {
    const int row = k * 16 + (t >> 4);
    const int a = gcode[sA + row];
    const float eA = E[sA + row];
    const float4 sv = *(const float4*)(St + row * 128 + l8 * 8);
    const _Float16* hp = (const _Float16*)&sv;
    float rsum = 0.f;
#pragma unroll
    for (int e = 0; e < 8; ++e) {
      const int col = l8 * 8 + e;
      const float em = __expf(-(float)hp[e]);
      const bool pos =
          (a == cb[e]) && (cb[e] <= 2) && !(diag && (row + h * 64) == col);
      rsum += pos ? __logf(1.f + eA * em) : 0.f;
      colsum[e] += pos ? __logf(1.f + eB[e] * em) : 0.f;
    }
#pragma unroll
    for (int off = 1; off < 16; off <<= 1) rsum += __shfl_xor(rsum, off);
    if (l8 == 0) {
      const size_t base = (sA + row) * SLOTW + bj * 4;
      P2[base + h * 2] = rsum;
      P2[base + h * 2 + 1] = 0.f;
      P2[base + (1 - h) * 2] = 0.f;
      P2[base + (1 - h) * 2 + 1] = 0.f;
    }
  }
  // cross-wave col reduction via LDS (stride 17: conflict-free)
  __shared__ float colpart[128 * 17];
#pragma unroll
  for (int e = 0; e < 8; ++e) colpart[(l8 * 8 + e) * 17 + (t >> 4)] = colsum[e];
  __syncthreads();
  if (t < 128 && !diag) {
    float cs = 0.f;
#pragma unroll
    for (int i = 0; i < 16; ++i) cs += colpart[t * 17 + i];
    const size_t base = (rowB + t) * SLOTW + bi * 4 + h * 2;
    P2[base] = cs;
    P2[base + 1] = 0.f;
  }
}

// ---------------- K6: final deterministic reduce ----------------------------
__global__ __launch_bounds__(256) void k_final(
    const float* __restrict__ psum, const float* __restrict__ E,
    const unsigned char* __restrict__ code, const int* __restrict__ dst,
    const int* __restrict__ hdr, float* __restrict__ out, int Nv) {
  const int t = threadIdx.x;
  const int c0 = hdr[4], c1 = hdr[5], c2 = hdr[6];
  const int validTotal = c0 + c1 + c2;
  const float em10 = __expf(-10.0f);
  double s = 0.0;
  int c = 0;
  for (int i = t; i < Nv; i += 256) {
    const int myc = code[i];
    if (myc > 2) continue;  // invalid anchor: not processed
    const int cmy = (myc == 0) ? c0 : ((myc == 1) ? c1 : c2);
    if (validTotal - cmy == 0) continue;  // no negatives: not processed
    const int g = dst[i];
    const int pos_cnt = cmy - 1;
    if (pos_cnt > 0) {
      s += (double)(psum[g] / (float)pos_cnt);
      c += 1;
    } else {
      s += (double)__logf(1.f + E[g] * em10);  // logaddexp(1/T,lse) - 1/T
    }
  }
#pragma unroll
  for (int off = 32; off; off >>= 1) {
    s += __shfl_down(s, off);
    c += __shfl_down(c, off);
  }
  __shared__ double sd[4];
  __shared__ int si[4];
  if ((t & 63) == 0) {
    sd[t >> 6] = s;
    si[t >> 6] = c;
  }
  __syncthreads();
  if (t == 0) {
    const double st = sd[0] + sd[1] + sd[2] + sd[3];
    const int ct = 1 + si[0] + si[1] + si[2] + si[3];
    out[0] = (float)(st / (double)ct);
  }
}

extern "C" void kernel_launch(void* const* d_in, const int* in_sizes, int n_in,
                              void* d_out, int out_size, void* d_ws,
                              size_t ws_size, hipStream_t stream) {
  const float* X = (const float*)d_in[0];
  const int* labels = (const int*)d_in[1];
  const int* bad = (const int*)d_in[2];
  const int Nv = in_sizes[1];
  const int Dv = in_sizes[0] / Nv;

  size_t off = 0;
  auto alloc = [&](size_t bytes) -> void* {
    size_t p = (off + 255) & ~(size_t)255;
    off = p + bytes;
    return (void*)((char*)d_ws + p);
  };
  const int NT = Nv / 128;
  const int ntri_max = NT * (NT + 1) / 2;
  __bf16* fng = (__bf16*)alloc((size_t)Nv * Dv * 2);
  float* P = (float*)alloc((size_t)Nv * SLOTW * 4);
  float* P2 = (float*)alloc((size_t)Nv * SLOTW * 4);
  _Float16* Sc = (_Float16*)alloc((size_t)ntri_max * 2 * 8192 * 2);
  float* E = (float*)alloc((size_t)Nv * 4);
  float* psum = (float*)alloc((size_t)Nv * 4);
  int* dst = (int*)alloc((size_t)Nv * 4);
  unsigned char* code = (unsigned char*)alloc((size_t)Nv);
  unsigned char* gcode = (unsigned char*)alloc((size_t)Nv);
  int* hdr = (int*)alloc(64);
  if (off > ws_size) return;  // scratch too small: fail loudly at validation

  k_scan<<<1, 1024, 0, stream>>>(labels, bad, code, dst, hdr, fng, gcode, Nv,
                                 Dv);
  k_norm<<<Nv, 128, 0, stream>>>(X, code, dst, fng, gcode, Dv);
  dim3 gp(ntri_max, 2);
  k_p1<<<gp, 256, 0, stream>>>(fng, gcode, hdr, P, Sc, Dv);
  k_red<<<(Nv + 255) / 256, 256, 0, stream>>>(P, E, hdr, Nv);
  k_p2<<<gp, 256, 0, stream>>>(gcode, hdr, E, P2, Sc);
  k_red<<<(Nv + 255) / 256, 256, 0, stream>>>(P2, psum, hdr, Nv);
  k_final<<<1, 256, 0, stream>>>(psum, E, code, dst, hdr, (float*)d_out, Nv);
}

// Round 12
// 147.277 us; speedup vs baseline: 1.2287x; 1.2158x over previous
//
#include <hip/hip_runtime.h>

typedef __bf16 bf16x8 __attribute__((ext_vector_type(8)));
typedef __bf16 bf16x4 __attribute__((ext_vector_type(4)));
typedef float f32x4 __attribute__((ext_vector_type(4)));

#define SLOTW 260  // per-row partial-slot stride floats (>= 4*NTv_max=256)

#define GLOAD_LDS16(g, l)                                                      \
  __builtin_amdgcn_global_load_lds(                                            \
      (const __attribute__((address_space(1))) void*)(g),                      \
      (__attribute__((address_space(3))) void*)(l), 16, 0, 0)

// ---------------- K1: codes + stable label-partition scan (1 block) ---------
// dst[r] = gathered index for valid rows, grouped by label (0,1,2 ascending).
// hdr = {M, Mpad, NTv, ntri, C0, C1, C2, count}. Also zeroes fng pad rows,
// sets gcode pad = 255, and zeroes out[0] (harness poisons it 0xAA).
__global__ __launch_bounds__(1024) void k_scan(
    const int* __restrict__ labels, const int* __restrict__ bad,
    unsigned char* __restrict__ code, int* __restrict__ dst,
    int* __restrict__ hdr, __bf16* __restrict__ fng,
    unsigned char* __restrict__ gcode, float* __restrict__ out, int Nv,
    int Dv) {
  const int t = threadIdx.x;
  const int per = Nv >> 10;  // rows per thread (8 for 8192)
  const int base = t * per;
  unsigned char lc[8];
  int cnt[3] = {0, 0, 0};
  for (int k = 0; k < per; ++k) {
    const int r = base + k;
    const unsigned char c =
        (bad[r] == 0) ? (unsigned char)labels[r] : (unsigned char)255;
    lc[k] = c;
    code[r] = c;
    if (c <= 2) cnt[c]++;
  }
  __shared__ int s0[1024], s1[1024], s2[1024];
  s0[t] = cnt[0];
  s1[t] = cnt[1];
  s2[t] = cnt[2];
  __syncthreads();
  for (int off = 1; off < 1024; off <<= 1) {
    const int a0 = (t >= off) ? s0[t - off] : 0;
    const int a1 = (t >= off) ? s1[t - off] : 0;
    const int a2 = (t >= off) ? s2[t - off] : 0;
    __syncthreads();
    s0[t] += a0;
    s1[t] += a1;
    s2[t] += a2;
    __syncthreads();
  }
  const int C0 = s0[1023], C1 = s1[1023], C2 = s2[1023];
  int run[3];
  run[0] = s0[t] - cnt[0];
  run[1] = C0 + s1[t] - cnt[1];
  run[2] = C0 + C1 + s2[t] - cnt[2];
  for (int k = 0; k < per; ++k) {
    const int c = lc[k];
    dst[base + k] = (c <= 2) ? run[c]++ : -1;
  }
  const int M = C0 + C1 + C2;
  const int Mpad = (M + 127) & ~127;
  if (t == 0) {
    const int NTv = Mpad >> 7;
    hdr[0] = M;
    hdr[1] = Mpad;
    hdr[2] = NTv;
    hdr[3] = NTv * (NTv + 1) / 2;
    hdr[4] = C0;
    hdr[5] = C1;
    hdr[6] = C2;
    // count = 1 + #(anchors processed & with positives):
    // anchor label l contributes C_l iff C_l>=2 (has pos) and M>C_l (has neg)
    int count = 1;
    if (C0 >= 2 && M > C0) count += C0;
    if (C1 >= 2 && M > C1) count += C1;
    if (C2 >= 2 && M > C2) count += C2;
    hdr[7] = count;
    out[0] = 0.f;  // k_fin atomicAdds into this
  }
  // pad rows: fng zero (MFMA reads them), gcode 255 (self-masking)
  for (int i = M + t; i < Mpad; i += 1024) gcode[i] = 255;
  const int nv4 = (Mpad - M) * (Dv >> 3);  // float4 chunks in pad region
  float4* fp = (float4*)(fng + (size_t)M * Dv);
  const float4 z = {0.f, 0.f, 0.f, 0.f};
  for (int i = t; i < nv4; i += 1024) fp[i] = z;
}

// ---------------- K2: normalize valid rows -> bf16, gathered+sorted ---------
__global__ __launch_bounds__(128) void k_norm(const float* __restrict__ X,
                                              const unsigned char* __restrict__
                                                  code,
                                              const int* __restrict__ dst,
                                              __bf16* __restrict__ fng,
                                              unsigned char* __restrict__ gcode,
                                              int Dv) {
  const int row = blockIdx.x;
  const unsigned char c = code[row];
  if (c > 2) return;  // invalid: skipped entirely
  const int g = dst[row];
  const int t = threadIdx.x;
  const float4* xr = (const float4*)(X + (size_t)row * Dv);
  float ss = 0.f;
  const int nv4 = Dv >> 2;
  for (int idx = t; idx < nv4; idx += 128) {
    float4 v = xr[idx];
    ss += v.x * v.x + v.y * v.y + v.z * v.z + v.w * v.w;
  }
#pragma unroll
  for (int off = 32; off; off >>= 1) ss += __shfl_down(ss, off);
  __shared__ float sred[2];
  if ((t & 63) == 0) sred[t >> 6] = ss;
  __syncthreads();
  const float inv = 1.0f / sqrtf(sred[0] + sred[1]);
  // one 16B bf16x8 store per 8 elements
  const int nv8 = Dv >> 3;
  for (int idx = t; idx < nv8; idx += 128) {
    const float4 v0 = xr[idx * 2];
    const float4 v1 = xr[idx * 2 + 1];
    bf16x8 o;
    o[0] = (__bf16)(v0.x * inv);
    o[1] = (__bf16)(v0.y * inv);
    o[2] = (__bf16)(v0.z * inv);
    o[3] = (__bf16)(v0.w * inv);
    o[4] = (__bf16)(v1.x * inv);
    o[5] = (__bf16)(v1.y * inv);
    o[6] = (__bf16)(v1.z * inv);
    o[7] = (__bf16)(v1.w * inv);
    *(bf16x8*)(fng + (size_t)g * Dv + idx * 8) = o;
  }
  if (t == 0) gcode[g] = c;
}

__device__ __forceinline__ void tri_decode(int blk, int NT, int& bi, int& bj) {
  int b = 0, rem = blk, span = NT;
  while (rem >= span) {
    rem -= span;
    b++;
    span--;
  }
  bi = b;
  bj = b + rem;
}

__device__ __forceinline__ bool tile_overlap(const unsigned char* gcode,
                                             size_t sA, size_t rowB) {
  const int la0 = gcode[sA], la1 = gcode[sA + 63];
  const int lb0 = gcode[rowB], lb1 = gcode[rowB + 127];
  const int hiA = la1 > 2 ? 2 : la1;
  const int hiB = lb1 > 2 ? 2 : lb1;
  const int lo = la0 > lb0 ? la0 : lb0;
  const int hi = hiA < hiB ? hiA : hiB;
  return (la0 <= 2) && (lb0 <= 2) && (lo <= hi);
}

// ---------------- K3: pass 1 — exp-sums, 64x128 half-tiles ------------------
// R9 config (measured optimum of the concurrency x issue-ratio trade):
// 256-thr/4-wave blocks, wave = 32x64 (2x4 of 16x16x32 MFMA), coalesced
// global_load_lds staging, double-buffered, one barrier/iter. 24 KB LDS.
// __launch_bounds__(256,6): cap VGPRs (~85) so 6 blocks/CU co-reside (VGPR=112
// capped at 4; LDS allows 6) — the loop is latency-bound on the barrier/vmcnt
// round trip and resident blocks are what hide it.
// Stores Sc (fp16 half-tile) for label-overlap tiles so pass 2 needs no MFMA.
// Slot ownership (P not pre-zeroed — every slot < 4*NTv single-written):
//   rows of half h: real slot bj*4+h*2+(wave&1), zero slot bj*4+(1-h)*2+(wave&1)
//   cols (bi<bj): real slot bi*4+h*2+(wave>>1)   [all 4 across h x wavehalf]
__global__ __launch_bounds__(256, 6) void k_p1(
    const __bf16* __restrict__ fng, const unsigned char* __restrict__ gcode,
    const int* __restrict__ hdr, float* __restrict__ P,
    _Float16* __restrict__ Sc, int Dv) {
  const int NTv = hdr[2];
  if ((int)blockIdx.x >= hdr[3]) return;
  int bi, bj;
  tri_decode(blockIdx.x, NTv, bi, bj);
  const int h = blockIdx.y;
  const size_t sA = (size_t)bi * 128 + h * 64;
  const size_t rowB = (size_t)bj * 128;
  __shared__ __align__(16) __bf16 As[2][64 * 32];
  __shared__ __align__(16) __bf16 Bs[2][128 * 32];

  const int t = threadIdx.x;
  const int lane = t & 63;
  const int wave = t >> 6;
  const int quad = lane >> 4;
  const int l16 = lane & 15;
  const int wr = (wave >> 1) * 32;
  const int wc = (wave & 1) * 64;
  const int r4 = t >> 2, q4 = t & 3;
  const int r4b = (t + 256) >> 2, q4b = (t + 256) & 3;

  f32x4 acc[2][4] = {};
  auto stage = [&](int k0, int b) {
    GLOAD_LDS16(fng + (sA + r4) * Dv + k0 + q4 * 8,
                &As[b][(size_t)wave * 64 * 8]);
    GLOAD_LDS16(fng + (rowB + r4) * Dv + k0 + q4 * 8,
                &Bs[b][(size_t)wave * 64 * 8]);
    GLOAD_LDS16(fng + (rowB + r4b) * Dv + k0 + q4b * 8,
                &Bs[b][(size_t)(256 + wave * 64) * 8]);
  };
  stage(0, 0);
  int buf = 0;
  for (int k0 = 0; k0 < Dv; k0 += 32) {
    __syncthreads();  // drains vmcnt: buf's loads complete; prev reads done
    if (k0 + 32 < Dv) stage(k0 + 32, buf ^ 1);  // flies under this iter's MFMA
    bf16x8 af[2], bfv[4];
#pragma unroll
    for (int mi = 0; mi < 2; ++mi)
      af[mi] = *(const bf16x8*)&As[buf][(wr + mi * 16 + l16) * 32 + quad * 8];
#pragma unroll
    for (int ni = 0; ni < 4; ++ni)
      bfv[ni] = *(const bf16x8*)&Bs[buf][(wc + ni * 16 + l16) * 32 + quad * 8];
#pragma unroll
    for (int mi = 0; mi < 2; ++mi)
#pragma unroll
      for (int ni = 0; ni < 4; ++ni)
        acc[mi][ni] = __builtin_amdgcn_mfma_f32_16x16x32_bf16(
            af[mi], bfv[ni], acc[mi][ni], 0, 0, 0);
    buf ^= 1;
  }

  // C/D layout (verified m89/m91): col = lane&15, row = quad*4 + reg
  unsigned char ca[8], cb[4];
#pragma unroll
  for (int mi = 0; mi < 2; ++mi)
#pragma unroll
    for (int r = 0; r < 4; ++r)
      ca[mi * 4 + r] = gcode[sA + wr + mi * 16 + quad * 4 + r];
#pragma unroll
  for (int ni = 0; ni < 4; ++ni) cb[ni] = gcode[rowB + wc + ni * 16 + l16];
  const bool ov = tile_overlap(gcode, sA, rowB);
  _Float16* St = Sc + ((size_t)blockIdx.x * 2 + h) * 8192;

  float rowsum[8] = {};
  float colsum[4] = {};
#pragma unroll
  for (int mi = 0; mi < 2; ++mi)
#pragma unroll
    for (int ni = 0; ni < 4; ++ni)
#pragma unroll
      for (int r = 0; r < 4; ++r) {
        const float s = acc[mi][ni][r] * 10.0f;
        const float ex = __expf(s);
        const int a = ca[mi * 4 + r], b = cb[ni];
        const bool diff = a != b;
        rowsum[mi * 4 + r] += (b <= 2 && diff) ? ex : 0.f;
        colsum[ni] += (a <= 2 && diff) ? ex : 0.f;
        if (ov)
          St[(wr + mi * 16 + quad * 4 + r) * 128 + wc + ni * 16 + l16] =
              (_Float16)s;
      }
#pragma unroll
  for (int off = 1; off < 16; off <<= 1)
#pragma unroll
    for (int k = 0; k < 8; ++k) rowsum[k] += __shfl_xor(rowsum[k], off);
  if (l16 == 0)
#pragma unroll
    for (int k = 0; k < 8; ++k) {
      const size_t base =
          (sA + wr + (k >> 2) * 16 + quad * 4 + (k & 3)) * SLOTW + bj * 4;
      P[base + h * 2 + (wave & 1)] = rowsum[k];
      P[base + (1 - h) * 2 + (wave & 1)] = 0.f;
    }
  if (bi != bj) {
#pragma unroll
    for (int off = 16; off < 64; off <<= 1)
#pragma unroll
      for (int ni = 0; ni < 4; ++ni) colsum[ni] += __shfl_xor(colsum[ni], off);
    if (quad == 0)
#pragma unroll
      for (int ni = 0; ni < 4; ++ni)
        P[(rowB + wc + ni * 16 + l16) * SLOTW + bi * 4 + h * 2 + (wave >> 1)] =
            colsum[ni];
  }
}

// ---------------- K4: slot reduce: E[g] = sum_{slot<4*NTv} P[g*SLOTW+..] ----
__global__ __launch_bounds__(256) void k_red(const float* __restrict__ P,
                                             float* __restrict__ out,
                                             const int* __restrict__ hdr,
                                             int Nv) {
  const int g = blockIdx.x * 256 + threadIdx.x;
  if (g >= Nv || g >= hdr[1]) return;  // only gathered rows matter
  const int ns = hdr[2] * 4;
  float s = 0.f;
  const float4* p = (const float4*)(P + (size_t)g * SLOTW);
  for (int k = 0; k < (ns >> 2); ++k) {
    const float4 v = p[k];
    s += v.x + v.y + v.z + v.w;
  }
  out[g] = s;
}

// ---------------- K5: pass 2 — positive log-terms from stored Sc ------------
// No MFMA: reads the fp16 half-tile p1 stored (only for overlap tiles).
// Slot ownership (P2): row g (half h): all 4 slots bj*4+{0..3} (real at h*2,
// zeros elsewhere); col j: slots bi*4+h*2+{0,1} (real at +0, zero at +1).
// Inactive blocks zero their owned slots — deterministic, no memset.
__global__ __launch_bounds__(256) void k_p2(
    const unsigned char* __restrict__ gcode, const int* __restrict__ hdr,
    const float* __restrict__ E, float* __restrict__ P2,
    const _Float16* __restrict__ Sc) {
  const int NTv = hdr[2];
  if ((int)blockIdx.x >= hdr[3]) return;
  int bi, bj;
  tri_decode(blockIdx.x, NTv, bi, bj);
  const int h = blockIdx.y;
  const size_t sA = (size_t)bi * 128 + h * 64;
  const size_t rowB = (size_t)bj * 128;
  const int t = threadIdx.x;
  const bool diag = (bi == bj);

  if (!tile_overlap(gcode, sA, rowB)) {
    if (t < 64) {
      const size_t base = (sA + t) * SLOTW + bj * 4;
      P2[base] = 0.f;
      P2[base + 1] = 0.f;
      P2[base + 2] = 0.f;
      P2[base + 3] = 0.f;
    } else if (t < 192 && !diag) {
      const size_t base = (rowB + t - 64) * SLOTW + bi * 4 + h * 2;
      P2[base] = 0.f;
      P2[base + 1] = 0.f;
    }
    return;
  }

  const _Float16* St = Sc + ((size_t)blockIdx.x * 2 + h) * 8192;
  const int l8 = t & 15;  // column-chunk: cols l8*8 .. l8*8+7
  unsigned char cb[8];
  float eB[8];
  {
    const uint2 cv = *(const uint2*)(gcode + rowB + l8 * 8);
    const unsigned char* cp = (const unsigned char*)&cv;
#pragma unroll
    for (int e = 0; e < 8; ++e) cb[e] = cp[e];
    const float4 e0 = *(const float4*)(E + rowB + l8 * 8);
    const float4 e1 = *(const float4*)(E + rowB + l8 * 8 + 4);
    eB[0] = e0.x; eB[1] = e0.y; eB[2] = e0.z; eB[3] = e0.w;
    eB[4] = e1.x; eB[5] = e1.y; eB[6] = e1.z; eB[7] = e1.w;
  }
  float colsum[8] = {};
#pragma unroll
  for (int k = 0; k < 4; ++k) {
    const int row = k * 16 + (t >> 4);
    const int a = gcode[sA + row];
    const float eA = E[sA + row];
    const float4 sv = *(const float4*)(St + row * 128 + l8 * 8);
    const _Float16* hp = (const _Float16*)&sv;
    float rsum = 0.f;
#pragma unroll
    for (int e = 0; e < 8; ++e) {
      const int col = l8 * 8 + e;
      const float em = __expf(-(float)hp[e]);
      const bool pos =
          (a == cb[e]) && (cb[e] <= 2) && !(diag && (row + h * 64) == col);
      rsum += pos ? __logf(1.f + eA * em) : 0.f;
      colsum[e] += pos ? __logf(1.f + eB[e] * em) : 0.f;
    }
#pragma unroll
    for (int off = 1; off < 16; off <<= 1) rsum += __shfl_xor(rsum, off);
    if (l8 == 0) {
      const size_t base = (sA + row) * SLOTW + bj * 4;
      P2[base + h * 2] = rsum;
      P2[base + h * 2 + 1] = 0.f;
      P2[base + (1 - h) * 2] = 0.f;
      P2[base + (1 - h) * 2 + 1] = 0.f;
    }
  }
  // cross-wave col reduction via LDS (stride 17: conflict-free)
  __shared__ float colpart[128 * 17];
#pragma unroll
  for (int e = 0; e < 8; ++e) colpart[(l8 * 8 + e) * 17 + (t >> 4)] = colsum[e];
  __syncthreads();
  if (t < 128 && !diag) {
    float cs = 0.f;
#pragma unroll
    for (int i = 0; i < 16; ++i) cs += colpart[t * 17 + i];
    const size_t base = (rowB + t) * SLOTW + bi * 4 + h * 2;
    P2[base] = cs;
    P2[base + 1] = 0.f;
  }
}

// ---------------- K6: fused slot-reduce + final loss ------------------------
// Iterates gathered rows directly (processed/pos_cnt derivable from gcode +
// label counts — no code/dst indirection). One fp32 atomicAdd per block of
// partial/count (count precomputed in k_scan; out zeroed there too).
__global__ __launch_bounds__(256) void k_fin(const float* __restrict__ P2,
                                             const float* __restrict__ E,
                                             const unsigned char* __restrict__
                                                 gcode,
                                             const int* __restrict__ hdr,
                                             float* __restrict__ out) {
  const int g = blockIdx.x * 256 + threadIdx.x;
  const int t = threadIdx.x;
  float contrib = 0.f;
  if (g < hdr[1]) {
    const int l = gcode[g];
    if (l <= 2) {
      const int c0 = hdr[4], c1 = hdr[5], c2 = hdr[6];
      const int vt = c0 + c1 + c2;
      const int cmy = (l == 0) ? c0 : ((l == 1) ? c1 : c2);
      if (vt - cmy > 0) {  // has negatives -> processed
        const int pos_cnt = cmy - 1;
        if (pos_cnt > 0) {
          const int ns = hdr[2] * 4;
          float s = 0.f;
          const float4* p = (const float4*)(P2 + (size_t)g * SLOTW);
          for (int k = 0; k < (ns >> 2); ++k) {
            const float4 v = p[k];
            s += v.x + v.y + v.z + v.w;
          }
          contrib = s / (float)pos_cnt;
        } else {
          contrib = __logf(1.f + E[g] * __expf(-10.0f));
        }
      }
    }
  }
#pragma unroll
  for (int off = 32; off; off >>= 1) contrib += __shfl_down(contrib, off);
  __shared__ float sd[4];
  if ((t & 63) == 0) sd[t >> 6] = contrib;
  __syncthreads();
  if (t == 0) {
    const float tot = sd[0] + sd[1] + sd[2] + sd[3];
    atomicAdd(out, tot / (float)hdr[7]);
  }
}

extern "C" void kernel_launch(void* const* d_in, const int* in_sizes, int n_in,
                              void* d_out, int out_size, void* d_ws,
                              size_t ws_size, hipStream_t stream) {
  const float* X = (const float*)d_in[0];
  const int* labels = (const int*)d_in[1];
  const int* bad = (const int*)d_in[2];
  const int Nv = in_sizes[1];
  const int Dv = in_sizes[0] / Nv;

  size_t off = 0;
  auto alloc = [&](size_t bytes) -> void* {
    size_t p = (off + 255) & ~(size_t)255;
    off = p + bytes;
    return (void*)((char*)d_ws + p);
  };
  const int NT = Nv / 128;
  const int ntri_max = NT * (NT + 1) / 2;
  __bf16* fng = (__bf16*)alloc((size_t)Nv * Dv * 2);
  float* P = (float*)alloc((size_t)Nv * SLOTW * 4);
  float* P2 = (float*)alloc((size_t)Nv * SLOTW * 4);
  _Float16* Sc = (_Float16*)alloc((size_t)ntri_max * 2 * 8192 * 2);
  float* E = (float*)alloc((size_t)Nv * 4);
  int* dst = (int*)alloc((size_t)Nv * 4);
  unsigned char* code = (unsigned char*)alloc((size_t)Nv);
  unsigned char* gcode = (unsigned char*)alloc((size_t)Nv);
  int* hdr = (int*)alloc(64);
  if (off > ws_size) return;  // scratch too small: fail loudly at validation

  k_scan<<<1, 1024, 0, stream>>>(labels, bad, code, dst, hdr, fng, gcode,
                                 (float*)d_out, Nv, Dv);
  k_norm<<<Nv, 128, 0, stream>>>(X, code, dst, fng, gcode, Dv);
  dim3 gp(ntri_max, 2);
  k_p1<<<gp, 256, 0, stream>>>(fng, gcode, hdr, P, Sc, Dv);
  k_red<<<(Nv + 255) / 256, 256, 0, stream>>>(P, E, hdr, Nv);
  k_p2<<<gp, 256, 0, stream>>>(gcode, hdr, E, P2, Sc);
  k_fin<<<(Nv + 255) / 256, 256, 0, stream>>>(P2, E, gcode, hdr,
                                              (float*)d_out);
}